// Round 6
// baseline (140.710 us; speedup 1.0000x reference)
//
#include <hip/hip_runtime.h>

typedef short bf16x8 __attribute__((ext_vector_type(8)));
typedef float f32x4  __attribute__((ext_vector_type(4)));

#define CAP 12

// ws layout (bytes)
#define WS_LOSS 0
#define WS_DONE 8
#define WS_EN   64       // 1024 f32 codebook norms = 4096 B
#define WS_EBF  4160     // 1024*64 bf16 (permuted) = 131072 B

// dynamic LDS carve (bytes) — 152 KB, 1 block/CU (8 waves = 2/SIMD)
#define L_EBF    0        // 131072 codebook
#define L_X      131072   // 16384: phase A = zbf (128 pos x 64 dim bf16, swz)
#define L_THR    131072   //   phase B: thr_l (256*4 = 1024)
#define L_CSLOT  132096   //   phase B: cslot (256*CAP*4 = 12288, ends 144384)
#define L_RM4    147456   // 256 pos x 4 K-fourths = 4096
#define L_CCNT   151552   // 1024
#define L_KCH    152576   // 1024
#define L_MPART  153600   // 128 pos x 4 chunk |z|-partials = 2048
#define L_TOTAL  155648

__device__ __forceinline__ unsigned short f2bf(float f) {
    unsigned u = __float_as_uint(f);
    return (unsigned short)((u + 0x7fffu + ((u >> 16) & 1u)) >> 16);  // RTNE
}

// numpy pairwise sum (n=64): 8 accumulators, ((r0+r1)+(r2+r3))+((r4+r5)+(r6+r7)).
__device__ __forceinline__ float np_pairwise_sumsq64(const float* a) {
    float r[8];
    #pragma unroll
    for (int j = 0; j < 8; ++j) r[j] = __fmul_rn(a[j], a[j]);
    #pragma unroll
    for (int i = 8; i < 64; i += 8)
        #pragma unroll
        for (int j = 0; j < 8; ++j)
            r[j] = __fadd_rn(r[j], __fmul_rn(a[i + j], a[i + j]));
    return __fadd_rn(
        __fadd_rn(__fadd_rn(r[0], r[1]), __fadd_rn(r[2], r[3])),
        __fadd_rn(__fadd_rn(r[4], r[5]), __fadd_rn(r[6], r[7])));
}

// K1: bf16 codebook in MFMA-B-fragment-permuted layout + per-code exact fp32
// norms (bit-identical np_pairwise order) + zero loss/done.
// ebf[tile(64)][chunk j(8)][row r(16)][8 bf16], code = tile*16+r.
__global__ __launch_bounds__(256) void prep_kernel(
    const float* __restrict__ emb, unsigned short* __restrict__ ebf,
    float* __restrict__ en_t,
    float* __restrict__ loss, int* __restrict__ done)
{
    int k = blockIdx.x * 256 + threadIdx.x;
    if (k == 0) { *loss = 0.0f; *done = 0; }
    if (k < 1024) {
        float e[64];
        #pragma unroll
        for (int l = 0; l < 64; ++l) e[l] = emb[k * 64 + l];
        en_t[k] = np_pairwise_sumsq64(e);      // bit-exact numpy enorm
        int tile = k >> 4, r = k & 15;
        #pragma unroll
        for (int j = 0; j < 8; ++j) {
            bf16x8 v;
            #pragma unroll
            for (int m = 0; m < 8; ++m) v[m] = (short)f2bf(e[j * 8 + m]);
            *(bf16x8*)(ebf + tile * 1024 + j * 128 + r * 8) = v;
        }
    }
}

// K2: fused VQ — latency-chain-minimized. 512 thr (8 waves), 256 pos/block,
// grid 256. Wave (pg=wv&1, kf=wv>>1): 128 pos x 256 codes. Per tile:
// 2 ds_read_b128 + 16 MFMA (8 independent rg chains) + 32 fmax -> 4x fewer
// B-reads and loop iters than R5, 8-way ILP for latency hiding.
// A-frags via swizzled bf16 LDS tile (2-phase staging, 16KB reused), one
// ds_read_b128 each. Margin exact fp32 via staging partials. Cross-round
// evidence: time tracks per-thread latency chain, not occupancy/pipes.
__global__ __launch_bounds__(512, 2)
void vq_kernel(
    const float* __restrict__ ze, const float* __restrict__ emb,
    const unsigned short* __restrict__ ebf, const float* __restrict__ en_t,
    float* __restrict__ out_zq, float* __restrict__ out_idxf,
    float* __restrict__ loss, int* __restrict__ done,
    float* __restrict__ out_loss)
{
    extern __shared__ char smem[];
    unsigned short* ebf_l = (unsigned short*)(smem + L_EBF);
    unsigned short* zbf   = (unsigned short*)(smem + L_X);
    float*          thr_l = (float*)(smem + L_THR);
    int*            cslot = (int*)(smem + L_CSLOT);
    float*          rm4   = (float*)(smem + L_RM4);
    int*            ccnt  = (int*)(smem + L_CCNT);
    int*            kch   = (int*)(smem + L_KCH);
    float*          mpart = (float*)(smem + L_MPART);

    const int t = threadIdx.x;
    const int n0 = blockIdx.x * 256;
    const int gbase = (n0 >> 12) * 262144 + (n0 & 4095);

    const int wv = t >> 6, lane = t & 63;
    const int r = lane & 15, q = lane >> 4;
    const int pg = wv & 1, kf = wv >> 1;
    const int wp = pg * 128;

    // ---- stage codebook -> LDS (512 thr x 16 x 16B vector copies) ----
    {
        const bf16x8* src = (const bf16x8*)ebf;
        bf16x8* dst = (bf16x8*)ebf_l;
        #pragma unroll 16
        for (int i = 0; i < 16; ++i) dst[t + i * 512] = src[t + i * 512];
    }

    // ---- stage zbf phase 0: pos 0..127 -> swizzled bf16 + |z| partials ----
    {
        const int p = t & 127, dc = t >> 7;       // 4 dim-chunks of 16
        const float* zp = ze + gbase + p;
        unsigned short us[16];
        float s = 0.0f;
        #pragma unroll
        for (int j = 0; j < 16; ++j) {
            const float v = zp[(dc * 16 + j) * 4096];
            us[j] = f2bf(v);
            s += fabsf(v);
        }
        const int sw = (p & 7) << 3;              // bank swizzle (ushort units)
        unsigned short* row = zbf + p * 64;
        *(bf16x8*)(row + ((dc * 16 + 0) ^ sw)) = *(bf16x8*)(us);
        *(bf16x8*)(row + ((dc * 16 + 8) ^ sw)) = *(bf16x8*)(us + 8);
        mpart[p * 4 + dc] = s;
    }
    __syncthreads();   // B1: zbf0 + mpart0 + ebf_l in flight->visible

    bf16x8 a[8][2];
    float marg_reg = 0.0f;

    // ---- A-build (pg0 waves) + exact fp32 margin (pos 0..127) ----
    if (pg == 0) {
        const int sw = (r & 7) << 3;
        #pragma unroll
        for (int rg = 0; rg < 8; ++rg) {
            const unsigned short* row = zbf + (rg * 16 + r) * 64;
            a[rg][0] = *(const bf16x8*)(row + ((q * 8) ^ sw));
            a[rg][1] = *(const bf16x8*)(row + ((32 + q * 8) ^ sw));
        }
    }
    if (t < 128) {
        const float S = mpart[t * 4 + 0] + mpart[t * 4 + 1]
                      + mpart[t * 4 + 2] + mpart[t * 4 + 3];
        marg_reg = 1.67e-5f * S + 2.0e-4f;        // R5/R6-proven filter margin
    }
    __syncthreads();   // B2: zbf0 reads done, safe to overwrite

    // ---- stage zbf phase 1: pos 128..255 ----
    {
        const int p = t & 127, dc = t >> 7;
        const float* zp = ze + gbase + 128 + p;
        unsigned short us[16];
        float s = 0.0f;
        #pragma unroll
        for (int j = 0; j < 16; ++j) {
            const float v = zp[(dc * 16 + j) * 4096];
            us[j] = f2bf(v);
            s += fabsf(v);
        }
        const int sw = (p & 7) << 3;
        unsigned short* row = zbf + p * 64;
        *(bf16x8*)(row + ((dc * 16 + 0) ^ sw)) = *(bf16x8*)(us);
        *(bf16x8*)(row + ((dc * 16 + 8) ^ sw)) = *(bf16x8*)(us + 8);
        mpart[p * 4 + dc] = s;
    }
    __syncthreads();   // B3

    // ---- A-build (pg1 waves) + margin (pos 128..255), then pass 1 ----
    if (pg == 1) {
        const int sw = (r & 7) << 3;
        #pragma unroll
        for (int rg = 0; rg < 8; ++rg) {
            const unsigned short* row = zbf + (rg * 16 + r) * 64;
            a[rg][0] = *(const bf16x8*)(row + ((q * 8) ^ sw));
            a[rg][1] = *(const bf16x8*)(row + ((32 + q * 8) ^ sw));
        }
    }
    if (t >= 128 && t < 256) {
        const int p = t - 128;
        const float S = mpart[p * 4 + 0] + mpart[p * 4 + 1]
                      + mpart[p * 4 + 2] + mpart[p * 4 + 3];
        marg_reg = 1.67e-5f * S + 2.0e-4f;
    }

    // wave's K-fourth: 16 tiles of 16 codes starting at tile kf*16
    const unsigned short* bptr = ebf_l + (kf * 16) * 1024 + q * 128 + r * 8;

    // ---- pass 1: per-row max of c = z.e over wave's 256 codes ----
    float rm[32];
    #pragma unroll
    for (int i = 0; i < 32; ++i) rm[i] = -1e30f;
    {
        bf16x8 pb0[2], pb1[2];
        pb0[0] = *(const bf16x8*)(bptr);
        pb1[0] = *(const bf16x8*)(bptr + 512);
        pb0[1] = *(const bf16x8*)(bptr + 1024);
        pb1[1] = *(const bf16x8*)(bptr + 1536);
        #pragma unroll 4
        for (int tile = 0; tile < 16; ++tile) {
            bf16x8 b0 = pb0[tile & 1], b1 = pb1[tile & 1];
            int nt = tile + 2; if (nt > 15) nt = 15;
            pb0[tile & 1] = *(const bf16x8*)(bptr + nt * 1024);
            pb1[tile & 1] = *(const bf16x8*)(bptr + nt * 1024 + 512);
            #pragma unroll
            for (int rg = 0; rg < 8; ++rg) {
                f32x4 c = {0.f, 0.f, 0.f, 0.f};
                c = __builtin_amdgcn_mfma_f32_16x16x32_bf16(a[rg][0], b0, c, 0, 0, 0);
                c = __builtin_amdgcn_mfma_f32_16x16x32_bf16(a[rg][1], b1, c, 0, 0, 0);
                #pragma unroll
                for (int i = 0; i < 4; ++i)
                    rm[rg * 4 + i] = fmaxf(rm[rg * 4 + i], c[i]);
            }
        }
    }
    // reduce over the 16 code-lanes, publish per-K-fourth rowmax
    #pragma unroll
    for (int j = 0; j < 32; ++j) {
        float v = rm[j];
        v = fmaxf(v, __shfl_xor(v, 1, 16));
        v = fmaxf(v, __shfl_xor(v, 2, 16));
        v = fmaxf(v, __shfl_xor(v, 4, 16));
        v = fmaxf(v, __shfl_xor(v, 8, 16));
        if (r == 0)
            rm4[(wp + (j >> 2) * 16 + q * 4 + (j & 3)) * 4 + kf] = v;
    }
    __syncthreads();   // B4: pass1 + rm4 publish done; zbf dead

    // ---- threshold: maxc over 4 K-fourths - marg/2; zero ccnt ----
    if (t < 256) {
        const float maxc = fmaxf(fmaxf(rm4[t * 4 + 0], rm4[t * 4 + 1]),
                                 fmaxf(rm4[t * 4 + 2], rm4[t * 4 + 3]));
        thr_l[t] = maxc - 0.5f * marg_reg;
        ccnt[t] = 0;
    }
    __syncthreads();   // B5

    // ---- pass 2: collect candidates ----
    {
        float thr[32];
        #pragma unroll
        for (int j = 0; j < 32; ++j)
            thr[j] = thr_l[wp + (j >> 2) * 16 + q * 4 + (j & 3)];
        bf16x8 pb0[2], pb1[2];
        pb0[0] = *(const bf16x8*)(bptr);
        pb1[0] = *(const bf16x8*)(bptr + 512);
        pb0[1] = *(const bf16x8*)(bptr + 1024);
        pb1[1] = *(const bf16x8*)(bptr + 1536);
        #pragma unroll 4
        for (int tile = 0; tile < 16; ++tile) {
            bf16x8 b0 = pb0[tile & 1], b1 = pb1[tile & 1];
            int nt = tile + 2; if (nt > 15) nt = 15;
            pb0[tile & 1] = *(const bf16x8*)(bptr + nt * 1024);
            pb1[tile & 1] = *(const bf16x8*)(bptr + nt * 1024 + 512);
            const int code = kf * 256 + tile * 16 + r;
            #pragma unroll
            for (int rg = 0; rg < 8; ++rg) {
                f32x4 c = {0.f, 0.f, 0.f, 0.f};
                c = __builtin_amdgcn_mfma_f32_16x16x32_bf16(a[rg][0], b0, c, 0, 0, 0);
                c = __builtin_amdgcn_mfma_f32_16x16x32_bf16(a[rg][1], b1, c, 0, 0, 0);
                #pragma unroll
                for (int i = 0; i < 4; ++i) {
                    if (c[i] >= thr[rg * 4 + i]) {
                        const int pp = wp + rg * 16 + q * 4 + i;
                        const int ci = atomicAdd(&ccnt[pp], 1);
                        if (ci < CAP) cslot[pp * CAP + ci] = code;
                    }
                }
            }
        }
    }
    __syncthreads();   // B6

    // ---- exact fp32 numpy rescore, 2 threads/position (candidate-strided);
    // enorm from precomputed table; dot in sequential numpy sgemm order.
    {
        const int p = t >> 1, cl = t & 1;
        int cnt = ccnt[p]; if (cnt > CAP) cnt = CAP;
        float z[64];
        const float* zp = ze + gbase + p;
        #pragma unroll
        for (int l = 0; l < 64; ++l) z[l] = zp[l * 4096];   // L3-hot reload
        const float znorm = np_pairwise_sumsq64(z);
        float best = 1e30f; int bk = 1 << 20;
        for (int c = cl; c < cnt; c += 2) {
            const int k = cslot[p * CAP + c];
            const float4* er = (const float4*)(emb + k * 64);
            float acc = 0.0f;
            #pragma unroll
            for (int jj = 0; jj < 16; ++jj) {
                const float4 v = er[jj];
                acc = fmaf(z[4 * jj + 0], v.x, acc);
                acc = fmaf(z[4 * jj + 1], v.y, acc);
                acc = fmaf(z[4 * jj + 2], v.z, acc);
                acc = fmaf(z[4 * jj + 3], v.w, acc);
            }
            const float sc = __fsub_rn(__fadd_rn(znorm, en_t[k]), __fmul_rn(2.0f, acc));
            if (sc < best || (sc == best && k < bk)) { best = sc; bk = k; }
        }
        // lex-(score,k) pair merge via shfl (adjacent lanes share a position)
        const float ob = __shfl_xor(best, 1, 64);
        const int   ok = __shfl_xor(bk, 1, 64);
        if (ob < best || (ob == best && ok < bk)) { best = ob; bk = ok; }
        if (cl == 0) {
            kch[p] = bk;
            out_idxf[n0 + p] = (float)bk;
        }
    }
    __syncthreads();   // B7

    // ---- epilogue: 512 threads, dims split (h = t>>8, 32 dims each) ----
    {
        const int p = t & 255, h = t >> 8;
        const int bk = kch[p];
        const float* er = emb + bk * 64 + h * 32;
        const float* zp = ze + gbase + p + (h * 32) * 4096;
        float* op = out_zq + gbase + p + (h * 32) * 4096;
        float ls = 0.0f;
        #pragma unroll
        for (int j = 0; j < 32; ++j) {
            const float qv = er[j];
            const float zv = zp[j * 4096];
            op[j * 4096] = qv;
            const float d = qv - zv;
            ls = fmaf(d, d, ls);
        }
        #pragma unroll
        for (int off = 32; off > 0; off >>= 1) ls += __shfl_down(ls, off, 64);
        if (lane == 0) atomicAdd(loss, ls);
    }

    // ---- last block finalizes loss (device-scope atomics) ----
    __syncthreads();
    if (t == 0) {
        __threadfence();
        int old = atomicAdd(done, 1);
        if (old == (int)gridDim.x - 1) {
            __threadfence();
            float total = atomicAdd(loss, 0.0f);   // coherent read
            *out_loss = 1.25f * total / 4194304.0f;
        }
    }
}

extern "C" void kernel_launch(void* const* d_in, const int* in_sizes, int n_in,
                              void* d_out, int out_size, void* d_ws, size_t ws_size,
                              hipStream_t stream)
{
    const float* ze  = (const float*)d_in[0];   // (16,64,64,64) fp32
    const float* emb = (const float*)d_in[1];   // (1024,64) fp32
    float* out = (float*)d_out;
    float* out_zq   = out;                 // 4194304
    float* out_loss = out + 4194304;       // 1
    float* out_idxf = out + 4194305;       // 65536

    char* w = (char*)d_ws;
    float*          ws_loss = (float*)(w + WS_LOSS);
    int*            ws_done = (int*)(w + WS_DONE);
    float*          ws_en   = (float*)(w + WS_EN);
    unsigned short* ebf     = (unsigned short*)(w + WS_EBF);

    // allow >64KB dynamic LDS (no-op if already permitted)
    static bool attr_set = false;
    if (!attr_set) {
        hipFuncSetAttribute((const void*)vq_kernel,
                            hipFuncAttributeMaxDynamicSharedMemorySize, L_TOTAL);
        attr_set = true;
    }

    prep_kernel<<<4, 256, 0, stream>>>(emb, ebf, ws_en, ws_loss, ws_done);
    vq_kernel<<<256, 512, L_TOTAL, stream>>>(ze, emb, ebf, ws_en, out_zq,
                                             out_idxf, ws_loss, ws_done, out_loss);
}

// Round 8
// 138.150 us; speedup vs baseline: 1.0185x; 1.0185x over previous
//
#include <hip/hip_runtime.h>

typedef short bf16x8 __attribute__((ext_vector_type(8)));
typedef float f32x4  __attribute__((ext_vector_type(4)));

#define CAP 12

// ws layout (bytes)
#define WS_LOSS 0
#define WS_DONE 8
#define WS_EN   64       // 1024 f32 codebook norms = 4096 B
#define WS_EBF  4160     // 1024*64 bf16 (permuted) = 131072 B

// dynamic LDS carve (bytes) — 143 KB, 1 block/CU (8 waves = 2/SIMD)
#define L_EBF    0        // 131072
#define L_MARG   131072   // 256*4 = 1024
#define L_CCNT   132096   // 1024
#define L_KCH    133120   // 1024
#define L_CSLOT  134144   // 256*CAP*4 = 12288
#define L_TOTAL  146432

__device__ __forceinline__ unsigned short f2bf(float f) {
    unsigned u = __float_as_uint(f);
    return (unsigned short)((u + 0x7fffu + ((u >> 16) & 1u)) >> 16);  // RTNE
}

// numpy pairwise sum (n=64): 8 accumulators, ((r0+r1)+(r2+r3))+((r4+r5)+(r6+r7)).
__device__ __forceinline__ float np_pairwise_sumsq64(const float* a) {
    float r[8];
    #pragma unroll
    for (int j = 0; j < 8; ++j) r[j] = __fmul_rn(a[j], a[j]);
    #pragma unroll
    for (int i = 8; i < 64; i += 8)
        #pragma unroll
        for (int j = 0; j < 8; ++j)
            r[j] = __fadd_rn(r[j], __fmul_rn(a[i + j], a[i + j]));
    return __fadd_rn(
        __fadd_rn(__fadd_rn(r[0], r[1]), __fadd_rn(r[2], r[3])),
        __fadd_rn(__fadd_rn(r[4], r[5]), __fadd_rn(r[6], r[7])));
}

// K1: bf16 codebook in MFMA-B-fragment-permuted layout + per-code exact fp32
// norms (bit-identical np_pairwise order) + zero loss/done.
// ebf[tile(64)][chunk j(8)][row r(16)][8 bf16], code = tile*16+r.
__global__ __launch_bounds__(256) void prep_kernel(
    const float* __restrict__ emb, unsigned short* __restrict__ ebf,
    float* __restrict__ en_t,
    float* __restrict__ loss, int* __restrict__ done)
{
    int k = blockIdx.x * 256 + threadIdx.x;
    if (k == 0) { *loss = 0.0f; *done = 0; }
    if (k < 1024) {
        float e[64];
        #pragma unroll
        for (int l = 0; l < 64; ++l) e[l] = emb[k * 64 + l];
        en_t[k] = np_pairwise_sumsq64(e);      // bit-exact numpy enorm
        int tile = k >> 4, r = k & 15;
        #pragma unroll
        for (int j = 0; j < 8; ++j) {
            bf16x8 v;
            #pragma unroll
            for (int m = 0; m < 8; ++m) v[m] = (short)f2bf(e[j * 8 + m]);
            *(bf16x8*)(ebf + tile * 1024 + j * 128 + r * 8) = v;
        }
    }
}

// K2: fused VQ — R5 structure + latency-depth fixes (R7 resubmit; R7 bench
// was an infra container failure: no OOB / hang / VGPR-overrun found on audit).
// 512 thr (8 waves), 256 pos/block, grid 256. Wave = 32 positions x ALL 1024
// codes. Cross-round evidence (R0/R5/R6): only the B-prefetch-depth-4 variant
// broke 76 us -> ds_read_b128 latency (~120cyc) vs ~35cyc/iter issue is the
// stall; depth 8 covers ~240cyc. Rescore z-loads hoisted above pass2 (latency
// hidden under MFMA). VGPR budget: 256 allowed at 8 waves/CU; R5 used 68.
__global__ __launch_bounds__(512, 2)
void vq_kernel(
    const float* __restrict__ ze, const float* __restrict__ emb,
    const unsigned short* __restrict__ ebf, const float* __restrict__ en_t,
    float* __restrict__ out_zq, float* __restrict__ out_idxf,
    float* __restrict__ loss, int* __restrict__ done,
    float* __restrict__ out_loss)
{
    extern __shared__ char smem[];
    unsigned short* ebf_l = (unsigned short*)(smem + L_EBF);
    float*          marg_l= (float*)(smem + L_MARG);
    int*            ccnt  = (int*)(smem + L_CCNT);
    int*            kch   = (int*)(smem + L_KCH);
    int*            cslot = (int*)(smem + L_CSLOT);

    const int t = threadIdx.x;
    const int n0 = blockIdx.x * 256;
    const int gbase = (n0 >> 12) * 262144 + (n0 & 4095);

    // ---- stage codebook -> LDS (512 thr x 16 x 16B vector copies) ----
    {
        const bf16x8* src = (const bf16x8*)ebf;
        bf16x8* dst = (bf16x8*)ebf_l;
        #pragma unroll 16
        for (int i = 0; i < 16; ++i) dst[t + i * 512] = src[t + i * 512];
    }

    // ---- A-fragments from global ze (L3-hot) + folded margin ----
    const int wv = t >> 6, lane = t & 63;
    const int r = lane & 15, q = lane >> 4;
    const int wp = wv * 32;                    // wave's 32 positions
    bf16x8 a[2][2];
    float sm[2] = {0.f, 0.f};
    #pragma unroll
    for (int rg = 0; rg < 2; ++rg) {
        const float* zb = ze + gbase + wp + rg * 16 + r;
        #pragma unroll
        for (int j = 0; j < 8; ++j) {
            const float v0 = zb[(q * 8 + j) * 4096];
            const float v1 = zb[(32 + q * 8 + j) * 4096];
            a[rg][0][j] = (short)f2bf(v0);
            a[rg][1][j] = (short)f2bf(v1);
            sm[rg] += fabsf(v0) + fabsf(v1);
        }
    }
    // margin: reduce |z|-partials over the 4 q-lane groups; q==0 lanes publish
    #pragma unroll
    for (int rg = 0; rg < 2; ++rg) {
        float s = sm[rg];
        s += __shfl_xor(s, 16, 64);
        s += __shfl_xor(s, 32, 64);
        if (q == 0) marg_l[wp + rg * 16 + r] = 1.67e-5f * s + 2.0e-4f;
    }
    if (t < 256) ccnt[t] = 0;
    __syncthreads();   // staging + marg + ccnt visible

    const unsigned short* bptr = ebf_l + q * 128 + r * 8;

    // ---- pass 1: per-row max of c = z.e over ALL 1024 codes (64 tiles) ----
    // B-prefetch ring depth 8: covers ds_read_b128 ~120cyc latency.
    float rm[8];
    #pragma unroll
    for (int i = 0; i < 8; ++i) rm[i] = -1e30f;
    {
        bf16x8 pb0[8], pb1[8];
        #pragma unroll
        for (int i = 0; i < 8; ++i) {
            pb0[i] = *(const bf16x8*)(bptr + i * 1024);
            pb1[i] = *(const bf16x8*)(bptr + i * 1024 + 512);
        }
        #pragma unroll 8
        for (int tile = 0; tile < 64; ++tile) {
            bf16x8 b0 = pb0[tile & 7], b1 = pb1[tile & 7];
            int nt = tile + 8; if (nt > 63) nt = 63;
            pb0[tile & 7] = *(const bf16x8*)(bptr + nt * 1024);
            pb1[tile & 7] = *(const bf16x8*)(bptr + nt * 1024 + 512);
            #pragma unroll
            for (int rg = 0; rg < 2; ++rg) {
                f32x4 c = {0.f, 0.f, 0.f, 0.f};
                c = __builtin_amdgcn_mfma_f32_16x16x32_bf16(a[rg][0], b0, c, 0, 0, 0);
                c = __builtin_amdgcn_mfma_f32_16x16x32_bf16(a[rg][1], b1, c, 0, 0, 0);
                #pragma unroll
                for (int i = 0; i < 4; ++i)
                    rm[rg * 4 + i] = fmaxf(rm[rg * 4 + i], c[i]);
            }
        }
    }
    // in-wave rowmax: reduce over the 16 code-lanes (no LDS, no barrier)
    #pragma unroll
    for (int j = 0; j < 8; ++j) {
        float v = rm[j];
        v = fmaxf(v, __shfl_xor(v, 1, 16));
        v = fmaxf(v, __shfl_xor(v, 2, 16));
        v = fmaxf(v, __shfl_xor(v, 4, 16));
        v = fmaxf(v, __shfl_xor(v, 8, 16));
        rm[j] = v;
    }
    // threshold: candidate iff c >= maxc - marg/2
    float thr[8];
    #pragma unroll
    for (int j = 0; j < 8; ++j) {
        const int row = wp + (j >> 2) * 16 + q * 4 + (j & 3);
        thr[j] = rm[j] - 0.5f * marg_l[row];
    }

    // ---- hoist rescore z-loads: issue now, latency hides under pass 2 ----
    float z[64];
    {
        const int p = t >> 1;
        const float* zp = ze + gbase + p;
        #pragma unroll
        for (int l = 0; l < 64; ++l) z[l] = zp[l * 4096];   // L3-hot, verbatim
    }

    // ---- pass 2: collect candidates (wave-private rows; LDS atomics) ----
    {
        bf16x8 pb0[8], pb1[8];
        #pragma unroll
        for (int i = 0; i < 8; ++i) {
            pb0[i] = *(const bf16x8*)(bptr + i * 1024);
            pb1[i] = *(const bf16x8*)(bptr + i * 1024 + 512);
        }
        #pragma unroll 8
        for (int tile = 0; tile < 64; ++tile) {
            bf16x8 b0 = pb0[tile & 7], b1 = pb1[tile & 7];
            int nt = tile + 8; if (nt > 63) nt = 63;
            pb0[tile & 7] = *(const bf16x8*)(bptr + nt * 1024);
            pb1[tile & 7] = *(const bf16x8*)(bptr + nt * 1024 + 512);
            const int code = tile * 16 + r;
            #pragma unroll
            for (int rg = 0; rg < 2; ++rg) {
                f32x4 c = {0.f, 0.f, 0.f, 0.f};
                c = __builtin_amdgcn_mfma_f32_16x16x32_bf16(a[rg][0], b0, c, 0, 0, 0);
                c = __builtin_amdgcn_mfma_f32_16x16x32_bf16(a[rg][1], b1, c, 0, 0, 0);
                #pragma unroll
                for (int i = 0; i < 4; ++i) {
                    if (c[i] >= thr[rg * 4 + i]) {
                        const int pp = wp + rg * 16 + q * 4 + i;
                        const int ci = atomicAdd(&ccnt[pp], 1);
                        if (ci < CAP) cslot[pp * CAP + ci] = code;
                    }
                }
            }
        }
    }
    __syncthreads();

    // ---- exact fp32 numpy rescore, 2 threads/position (candidate-strided);
    // enorm from precomputed table; dot in sequential numpy sgemm order.
    // z[] already in registers (hoisted). Next-candidate code prefetched.
    {
        const int p = t >> 1, cl = t & 1;
        int cnt = ccnt[p]; if (cnt > CAP) cnt = CAP;
        const float znorm = np_pairwise_sumsq64(z);
        float best = 1e30f; int bk = 1 << 20;
        int kcur = (cl < cnt) ? cslot[p * CAP + cl] : 0;
        for (int c = cl; c < cnt; c += 2) {
            const int k = kcur;
            const int ni = c + 2;
            kcur = (ni < cnt) ? cslot[p * CAP + ni] : 0;   // prefetch next code
            const float4* er = (const float4*)(emb + k * 64);
            float acc = 0.0f;
            #pragma unroll
            for (int jj = 0; jj < 16; ++jj) {
                const float4 v = er[jj];
                acc = fmaf(z[4 * jj + 0], v.x, acc);
                acc = fmaf(z[4 * jj + 1], v.y, acc);
                acc = fmaf(z[4 * jj + 2], v.z, acc);
                acc = fmaf(z[4 * jj + 3], v.w, acc);
            }
            const float sc = __fsub_rn(__fadd_rn(znorm, en_t[k]), __fmul_rn(2.0f, acc));
            if (sc < best || (sc == best && k < bk)) { best = sc; bk = k; }
        }
        // lex-(score,k) pair merge via shfl (adjacent lanes share a position)
        const float ob = __shfl_xor(best, 1, 64);
        const int   ok = __shfl_xor(bk, 1, 64);
        if (ob < best || (ob == best && ok < bk)) { best = ob; bk = ok; }
        if (cl == 0) {
            kch[p] = bk;
            out_idxf[n0 + p] = (float)bk;
        }
    }
    __syncthreads();

    // ---- epilogue: 512 threads, dims split (h = t>>8, 32 dims each).
    // Batch all loads first (er + zp), then store/accumulate.
    {
        const int p = t & 255, h = t >> 8;
        const int bk = kch[p];
        const float* er = emb + bk * 64 + h * 32;
        const float* zp = ze + gbase + p + (h * 32) * 4096;
        float* op = out_zq + gbase + p + (h * 32) * 4096;
        float ev[32], zv[32];
        #pragma unroll
        for (int j = 0; j < 32; ++j) ev[j] = er[j];
        #pragma unroll
        for (int j = 0; j < 32; ++j) zv[j] = zp[j * 4096];
        float ls = 0.0f;
        #pragma unroll
        for (int j = 0; j < 32; ++j) {
            op[j * 4096] = ev[j];
            const float d = ev[j] - zv[j];
            ls = fmaf(d, d, ls);
        }
        #pragma unroll
        for (int off = 32; off > 0; off >>= 1) ls += __shfl_down(ls, off, 64);
        if (lane == 0) atomicAdd(loss, ls);
    }

    // ---- last block finalizes loss (device-scope atomics) ----
    __syncthreads();
    if (t == 0) {
        __threadfence();
        int old = atomicAdd(done, 1);
        if (old == (int)gridDim.x - 1) {
            __threadfence();
            float total = atomicAdd(loss, 0.0f);   // coherent read
            *out_loss = 1.25f * total / 4194304.0f;
        }
    }
}

extern "C" void kernel_launch(void* const* d_in, const int* in_sizes, int n_in,
                              void* d_out, int out_size, void* d_ws, size_t ws_size,
                              hipStream_t stream)
{
    const float* ze  = (const float*)d_in[0];   // (16,64,64,64) fp32
    const float* emb = (const float*)d_in[1];   // (1024,64) fp32
    float* out = (float*)d_out;
    float* out_zq   = out;                 // 4194304
    float* out_loss = out + 4194304;       // 1
    float* out_idxf = out + 4194305;       // 65536

    char* w = (char*)d_ws;
    float*          ws_loss = (float*)(w + WS_LOSS);
    int*            ws_done = (int*)(w + WS_DONE);
    float*          ws_en   = (float*)(w + WS_EN);
    unsigned short* ebf     = (unsigned short*)(w + WS_EBF);

    // allow >64KB dynamic LDS (no-op if already permitted)
    static bool attr_set = false;
    if (!attr_set) {
        hipFuncSetAttribute((const void*)vq_kernel,
                            hipFuncAttributeMaxDynamicSharedMemorySize, L_TOTAL);
        attr_set = true;
    }

    prep_kernel<<<4, 256, 0, stream>>>(emb, ebf, ws_en, ws_loss, ws_done);
    vq_kernel<<<256, 512, L_TOTAL, stream>>>(ze, emb, ebf, ws_en, out_zq,
                                             out_idxf, ws_loss, ws_done, out_loss);
}